// Round 1
// baseline (393.640 us; speedup 1.0000x reference)
//
#include <hip/hip_runtime.h>

#define BS   8
#define SEQ  2048
#define DH   128
#define BQ   32
#define BK   64
#define NT   256
#define QSTRIDE (DH + 4)   // 132 floats: breaks power-of-2 bank stride
#define PSTRIDE (BK + 4)   // 68 floats

// Flash-style fp32 attention with key-padding mask.
// One block = (batch b, 32 query rows). K-loop truncated at valid_len[b]:
// reference's -1e6 mask underflows exp() to exactly 0.0f, so skipped tiles
// and zeroed partial-tile lanes are bit-identical to the reference softmax.
__global__ __launch_bounds__(NT, 2)
void attn_fwd(const float* __restrict__ Q, const float* __restrict__ K,
              const float* __restrict__ V, const int* __restrict__ vlens,
              float* __restrict__ Out) {
    __shared__ float Qs[BQ][QSTRIDE];
    __shared__ float KVs[BK][QSTRIDE];   // K tile, then reused for V tile
    __shared__ float Ps[BQ][PSTRIDE];    // raw scores, then softmax weights
    __shared__ float alpha_s[BQ];
    __shared__ float l_s[BQ];

    const int tid = threadIdx.x;
    const int b  = blockIdx.y;
    const int q0 = blockIdx.x * BQ;
    const int vl = vlens[b];
    const float scale = 0.088388347648318441f;  // 1/sqrt(128)

    const float* Qb = Q + ((size_t)b * SEQ + q0) * DH;
    const float* Kb = K + (size_t)b * SEQ * DH;
    const float* Vb = V + (size_t)b * SEQ * DH;

    // ---- load Q tile (32 x 128), coalesced float4 ----
    {
        const int r  = tid >> 5;          // 0..7
        const int c4 = (tid & 31) * 4;    // float4 column
        #pragma unroll
        for (int i = 0; i < 4; ++i) {
            const int row = i * 8 + r;
            *(float4*)&Qs[row][c4] = *(const float4*)(Qb + (size_t)row * DH + c4);
        }
    }

    // stage-specific thread mappings
    const int sty = tid >> 4, stx = tid & 15;   // S stage: 2 rows x 4 cols
    const int brow = tid >> 3, bpart = tid & 7; // softmax: 8 threads/row
    const int prg = tid >> 5, pcg = tid & 31;   // PV: 4 rows x 4 cols

    float m_run = -1e30f, l_run = 0.0f;
    float O[4][4];
    #pragma unroll
    for (int i = 0; i < 4; ++i)
        #pragma unroll
        for (int j = 0; j < 4; ++j) O[i][j] = 0.0f;

    const int ntiles = (vl + BK - 1) / BK;
    for (int t = 0; t < ntiles; ++t) {
        const int k0 = t * BK;
        __syncthreads();  // prev tile's PV done with KVs/Ps

        // ---- load K tile (64 x 128) ----
        {
            const int r  = tid >> 5;
            const int c4 = (tid & 31) * 4;
            #pragma unroll
            for (int i = 0; i < 8; ++i) {
                const int row = i * 8 + r;
                *(float4*)&KVs[row][c4] =
                    *(const float4*)(Kb + (size_t)(k0 + row) * DH + c4);
            }
        }
        __syncthreads();

        // ---- S = Q K^T (each thread: 2 rows x 4 cols) ----
        float s0[4] = {0.f, 0.f, 0.f, 0.f};
        float s1[4] = {0.f, 0.f, 0.f, 0.f};
        #pragma unroll 2
        for (int d = 0; d < DH; d += 4) {
            const float4 qa = *(const float4*)&Qs[2 * sty][d];
            const float4 qb = *(const float4*)&Qs[2 * sty + 1][d];
            #pragma unroll
            for (int j = 0; j < 4; ++j) {
                const float4 kk = *(const float4*)&KVs[4 * stx + j][d];
                s0[j] += qa.x * kk.x + qa.y * kk.y + qa.z * kk.z + qa.w * kk.w;
                s1[j] += qb.x * kk.x + qb.y * kk.y + qb.z * kk.z + qb.w * kk.w;
            }
        }
        #pragma unroll
        for (int j = 0; j < 4; ++j) {
            const int kk = k0 + 4 * stx + j;
            const bool valid = kk < vl;
            Ps[2 * sty][4 * stx + j]     = valid ? s0[j] * scale : -1e30f;
            Ps[2 * sty + 1][4 * stx + j] = valid ? s1[j] * scale : -1e30f;
        }
        __syncthreads();  // Ps raw ready; KVs (K) free

        // ---- issue V global->reg loads (latency hidden under softmax) ----
        float4 vreg[8];
        {
            const int r  = tid >> 5;
            const int c4 = (tid & 31) * 4;
            #pragma unroll
            for (int i = 0; i < 8; ++i)
                vreg[i] = *(const float4*)(Vb + (size_t)(k0 + i * 8 + r) * DH + c4);
        }

        // ---- online softmax (8 threads per row, each 8 cols) ----
        float vals[8];
        float lm = -1e30f;
        #pragma unroll
        for (int i = 0; i < 8; ++i) {
            vals[i] = Ps[brow][bpart * 8 + i];
            lm = fmaxf(lm, vals[i]);
        }
        #pragma unroll
        for (int off = 1; off < 8; off <<= 1)
            lm = fmaxf(lm, __shfl_xor(lm, off, 64));
        const float m_new = fmaxf(m_run, lm);
        const float alpha = __expf(m_run - m_new);
        float psum = 0.0f;
        #pragma unroll
        for (int i = 0; i < 8; ++i) {
            const float p = __expf(vals[i] - m_new);
            Ps[brow][bpart * 8 + i] = p;
            psum += p;
        }
        #pragma unroll
        for (int off = 1; off < 8; off <<= 1)
            psum += __shfl_xor(psum, off, 64);
        l_run = l_run * alpha + psum;
        m_run = m_new;
        if (bpart == 0) alpha_s[brow] = alpha;

        // ---- commit V tile to LDS (overwrites K; safe post-barrier) ----
        {
            const int r  = tid >> 5;
            const int c4 = (tid & 31) * 4;
            #pragma unroll
            for (int i = 0; i < 8; ++i)
                *(float4*)&KVs[i * 8 + r][c4] = vreg[i];
        }
        __syncthreads();  // p, alpha_s, V all visible

        // ---- O = O*alpha + P V (each thread: 4 rows x 4 cols) ----
        float al[4];
        #pragma unroll
        for (int i = 0; i < 4; ++i) al[i] = alpha_s[prg * 4 + i];
        #pragma unroll
        for (int i = 0; i < 4; ++i)
            #pragma unroll
            for (int j = 0; j < 4; ++j) O[i][j] *= al[i];

        for (int k = 0; k < BK; k += 4) {
            float4 pr[4];
            #pragma unroll
            for (int i = 0; i < 4; ++i)
                pr[i] = *(const float4*)&Ps[prg * 4 + i][k];
            #pragma unroll
            for (int k2 = 0; k2 < 4; ++k2) {
                const float4 vv = *(const float4*)&KVs[k + k2][pcg * 4];
                #pragma unroll
                for (int i = 0; i < 4; ++i) {
                    const float p = ((const float*)&pr[i])[k2];
                    O[i][0] += p * vv.x;
                    O[i][1] += p * vv.y;
                    O[i][2] += p * vv.z;
                    O[i][3] += p * vv.w;
                }
            }
        }
    }

    // ---- publish per-row l, then normalized epilogue ----
    if (bpart == 0) l_s[brow] = l_run;
    __syncthreads();

    float* Ob = Out + ((size_t)b * SEQ + q0) * DH;
    #pragma unroll
    for (int i = 0; i < 4; ++i) {
        const int row = prg * 4 + i;
        const float inv = 1.0f / l_s[row];
        float4 o;
        o.x = O[i][0] * inv;
        o.y = O[i][1] * inv;
        o.z = O[i][2] * inv;
        o.w = O[i][3] * inv;
        *(float4*)(Ob + (size_t)row * DH + pcg * 4) = o;
    }
}

extern "C" void kernel_launch(void* const* d_in, const int* in_sizes, int n_in,
                              void* d_out, int out_size, void* d_ws, size_t ws_size,
                              hipStream_t stream) {
    const float* Q = (const float*)d_in[0];
    const float* K = (const float*)d_in[1];
    const float* V = (const float*)d_in[2];
    const int* vlens = (const int*)d_in[3];
    float* Out = (float*)d_out;

    dim3 grid(SEQ / BQ, BS, 1);   // (64, 8)
    dim3 block(NT, 1, 1);
    attn_fwd<<<grid, block, 0, stream>>>(Q, K, V, vlens, Out);
}

// Round 2
// 148.562 us; speedup vs baseline: 2.6497x; 2.6497x over previous
//
#include <hip/hip_runtime.h>

typedef float f32x4 __attribute__((ext_vector_type(4)));
typedef short bf16x8 __attribute__((ext_vector_type(8)));

#define BS   8
#define SEQ  2048
#define DH   128
#define BQ   32
#define BK   64
#define NT   256

#define KST  136   // K hi/lo LDS row stride (ushort): 272 B -> 2-way bank alias (free)
#define VST  72    // Vt LDS row stride (ushort): 144 B -> 2-way
#define PSST 68    // S fp32 LDS row stride (float): 272 B
#define PBST 72    // P bf16 LDS row stride (ushort): 144 B

__device__ __forceinline__ unsigned short f2bf(float x) {
    unsigned u = __float_as_uint(x);
    u += 0x7FFFu + ((u >> 16) & 1u);   // RNE
    return (unsigned short)(u >> 16);
}
__device__ __forceinline__ float bf2f(unsigned short h) {
    return __uint_as_float(((unsigned)h) << 16);
}

// ---- pre-pass 1: Q,K -> hi/lo bf16 (hi = bf16(x), lo = bf16(x - hi)) ----
__global__ __launch_bounds__(NT)
void conv_hilo(const float* __restrict__ Q, const float* __restrict__ K,
               unsigned short* __restrict__ Qhi, unsigned short* __restrict__ Qlo,
               unsigned short* __restrict__ Khi, unsigned short* __restrict__ Klo) {
    const int gid = blockIdx.x * NT + threadIdx.x;
    const int half = (BS * SEQ * DH) / 4;   // float4 groups per tensor
    const float* src;
    unsigned short *dhi, *dlo;
    int idx;
    if (gid < half) { src = Q; dhi = Qhi; dlo = Qlo; idx = gid; }
    else            { src = K; dhi = Khi; dlo = Klo; idx = gid - half; }
    float4 v = ((const float4*)src)[idx];
    ushort4 hi, lo;
    hi.x = f2bf(v.x); lo.x = f2bf(v.x - bf2f(hi.x));
    hi.y = f2bf(v.y); lo.y = f2bf(v.y - bf2f(hi.y));
    hi.z = f2bf(v.z); lo.z = f2bf(v.z - bf2f(hi.z));
    hi.w = f2bf(v.w); lo.w = f2bf(v.w - bf2f(hi.w));
    ((ushort4*)dhi)[idx] = hi;
    ((ushort4*)dlo)[idx] = lo;
}

// ---- pre-pass 2: V[b][s][d] -> Vt[b][d][s] bf16 (LDS tile transpose) ----
__global__ __launch_bounds__(NT)
void conv_vt(const float* __restrict__ V, unsigned short* __restrict__ Vt) {
    __shared__ unsigned short T[128][132];
    const int tid = threadIdx.x;
    const int b = blockIdx.y, s0 = blockIdx.x * 128;
    const float* Vb = V + ((size_t)b * SEQ + s0) * DH;
    #pragma unroll
    for (int p = 0; p < 16; ++p) {
        const int s = p * 8 + (tid >> 5);
        const int c = (tid & 31) * 4;
        float4 v = *(const float4*)(Vb + (size_t)s * DH + c);
        ushort4 h;
        h.x = f2bf(v.x); h.y = f2bf(v.y); h.z = f2bf(v.z); h.w = f2bf(v.w);
        *(ushort4*)&T[s][c] = h;
    }
    __syncthreads();
    unsigned short* Vtb = Vt + (size_t)b * DH * SEQ + s0;
    #pragma unroll
    for (int p = 0; p < 8; ++p) {
        const int d = p * 16 + (tid >> 4);
        const int ch = (tid & 15) * 8;
        ushort4 a, bq;
        a.x = T[ch + 0][d]; a.y = T[ch + 1][d]; a.z = T[ch + 2][d]; a.w = T[ch + 3][d];
        bq.x = T[ch + 4][d]; bq.y = T[ch + 5][d]; bq.z = T[ch + 6][d]; bq.w = T[ch + 7][d];
        *(ushort4*)(Vtb + (size_t)d * SEQ + ch) = a;
        *(ushort4*)(Vtb + (size_t)d * SEQ + ch + 4) = bq;
    }
}

// ---- main: flash attention, bf16 MFMA, hi/lo-split QK^T ----
__global__ __launch_bounds__(NT, 2)
void attn_mfma(const unsigned short* __restrict__ Qhi, const unsigned short* __restrict__ Qlo,
               const unsigned short* __restrict__ Khi, const unsigned short* __restrict__ Klo,
               const unsigned short* __restrict__ Vt, const int* __restrict__ vlens,
               float* __restrict__ Out) {
    __shared__ unsigned short Khs[BK][KST];
    __shared__ unsigned short Kls[BK][KST];
    __shared__ unsigned short Vts[DH][VST];
    __shared__ float Ps[BQ][PSST];          // S fp32; low 4608 B aliased as P bf16
    __shared__ float alphas[BQ];
    __shared__ float ls[BQ];
    unsigned short* Pbf = (unsigned short*)&Ps[0][0];

    const int tid = threadIdx.x;
    const int wid = tid >> 6, lane = tid & 63;
    const int quad = lane >> 4, l16 = lane & 15;
    const int b = blockIdx.y, q0 = blockIdx.x * BQ;
    const int vl = vlens[b];
    const float scale = 0.088388347648318441f;   // 1/sqrt(128)

    const size_t bQoff = ((size_t)b * SEQ + q0) * DH;
    const unsigned short* Khb = Khi + (size_t)b * SEQ * DH;
    const unsigned short* Klb = Klo + (size_t)b * SEQ * DH;
    const unsigned short* Vtb = Vt + (size_t)b * DH * SEQ;

    // Q fragments live in registers for the whole K-loop (A-operand layout:
    // m = lane&15, k = quad*8+j -> 8 contiguous d-elements = one 16 B load)
    bf16x8 qh[2][4], ql[2][4];
    #pragma unroll
    for (int mt = 0; mt < 2; ++mt)
        #pragma unroll
        for (int ks = 0; ks < 4; ++ks) {
            const size_t off = bQoff + (size_t)(16 * mt + l16) * DH + 32 * ks + 8 * quad;
            qh[mt][ks] = *(const bf16x8*)(Qhi + off);
            ql[mt][ks] = *(const bf16x8*)(Qlo + off);
        }

    f32x4 o[2][2];
    #pragma unroll
    for (int mt = 0; mt < 2; ++mt)
        #pragma unroll
        for (int nt = 0; nt < 2; ++nt)
            o[mt][nt] = (f32x4){0.f, 0.f, 0.f, 0.f};
    float m_run = -1e30f, l_run = 0.f;

    const int srow = tid >> 3, spart = tid & 7;   // softmax: 8 threads/row

    const int ntiles = (vl + BK - 1) / BK;
    for (int t = 0; t < ntiles; ++t) {
        const int k0 = t * BK;
        __syncthreads();   // prev iteration's LDS reads done

        // stage K hi/lo (64x128) and Vt (128x64) tiles
        {
            const int r = tid >> 4, c = (tid & 15) * 8;
            #pragma unroll
            for (int p = 0; p < 4; ++p) {
                const int row = p * 16 + r;
                *(uint4*)&Khs[row][c] = *(const uint4*)(Khb + (size_t)(k0 + row) * DH + c);
                *(uint4*)&Kls[row][c] = *(const uint4*)(Klb + (size_t)(k0 + row) * DH + c);
            }
            const int vr = tid >> 3, vc = (tid & 7) * 8;
            #pragma unroll
            for (int p = 0; p < 4; ++p) {
                const int d = p * 32 + vr;
                *(uint4*)&Vts[d][vc] = *(const uint4*)(Vtb + (size_t)d * SEQ + k0 + vc);
            }
        }
        __syncthreads();

        // ---- S = Q K^T, hi/lo split; wave computes cols 16*wid..+15 ----
        {
            bf16x8 bh[4], bl[4];
            #pragma unroll
            for (int ks = 0; ks < 4; ++ks) {
                const int koff = 32 * ks + 8 * quad;
                bh[ks] = *(const bf16x8*)&Khs[16 * wid + l16][koff];
                bl[ks] = *(const bf16x8*)&Kls[16 * wid + l16][koff];
            }
            #pragma unroll
            for (int mt = 0; mt < 2; ++mt) {
                f32x4 acc = (f32x4){0.f, 0.f, 0.f, 0.f};
                #pragma unroll
                for (int ks = 0; ks < 4; ++ks) {
                    acc = __builtin_amdgcn_mfma_f32_16x16x32_bf16(qh[mt][ks], bh[ks], acc, 0, 0, 0);
                    acc = __builtin_amdgcn_mfma_f32_16x16x32_bf16(qh[mt][ks], bl[ks], acc, 0, 0, 0);
                    acc = __builtin_amdgcn_mfma_f32_16x16x32_bf16(ql[mt][ks], bh[ks], acc, 0, 0, 0);
                }
                #pragma unroll
                for (int r = 0; r < 4; ++r)
                    Ps[16 * mt + 4 * quad + r][16 * wid + l16] = acc[r] * scale;
            }
        }
        __syncthreads();

        // ---- online softmax over this tile's 64 cols ----
        {
            float v[8];
            const float4 a = *(const float4*)&Ps[srow][spart * 8];
            const float4 c = *(const float4*)&Ps[srow][spart * 8 + 4];
            v[0] = a.x; v[1] = a.y; v[2] = a.z; v[3] = a.w;
            v[4] = c.x; v[5] = c.y; v[6] = c.z; v[7] = c.w;
            #pragma unroll
            for (int i = 0; i < 8; ++i)
                if (k0 + spart * 8 + i >= vl) v[i] = -1e30f;
            float lm = v[0];
            #pragma unroll
            for (int i = 1; i < 8; ++i) lm = fmaxf(lm, v[i]);
            lm = fmaxf(lm, __shfl_xor(lm, 1, 64));
            lm = fmaxf(lm, __shfl_xor(lm, 2, 64));
            lm = fmaxf(lm, __shfl_xor(lm, 4, 64));
            const float m_new = fmaxf(m_run, lm);
            const float alpha = __expf(m_run - m_new);
            float p[8], psum = 0.f;
            #pragma unroll
            for (int i = 0; i < 8; ++i) { p[i] = __expf(v[i] - m_new); psum += p[i]; }
            psum += __shfl_xor(psum, 1, 64);
            psum += __shfl_xor(psum, 2, 64);
            psum += __shfl_xor(psum, 4, 64);
            l_run = l_run * alpha + psum;
            m_run = m_new;
            if (spart == 0) alphas[srow] = alpha;
            __syncthreads();   // everyone done reading S fp32 before bf16 overwrite
            unsigned short pb[8] __attribute__((aligned(16)));
            #pragma unroll
            for (int i = 0; i < 8; ++i) pb[i] = f2bf(p[i]);
            *(uint4*)&Pbf[srow * PBST + spart * 8] = *(uint4*)pb;
        }
        __syncthreads();

        // ---- O = O*alpha + P V; wave computes d-cols 32*wid..+31 ----
        {
            bf16x8 pa[2][2], vb[2][2];
            #pragma unroll
            for (int mt = 0; mt < 2; ++mt)
                #pragma unroll
                for (int kk = 0; kk < 2; ++kk)
                    pa[mt][kk] = *(const bf16x8*)&Pbf[(16 * mt + l16) * PBST + 32 * kk + 8 * quad];
            #pragma unroll
            for (int nt = 0; nt < 2; ++nt)
                #pragma unroll
                for (int kk = 0; kk < 2; ++kk)
                    vb[nt][kk] = *(const bf16x8*)&Vts[32 * wid + 16 * nt + l16][32 * kk + 8 * quad];
            #pragma unroll
            for (int mt = 0; mt < 2; ++mt) {
                const float4 al = *(const float4*)&alphas[16 * mt + 4 * quad];
                #pragma unroll
                for (int nt = 0; nt < 2; ++nt) {
                    f32x4 x = o[mt][nt];
                    x[0] *= al.x; x[1] *= al.y; x[2] *= al.z; x[3] *= al.w;
                    x = __builtin_amdgcn_mfma_f32_16x16x32_bf16(pa[mt][0], vb[nt][0], x, 0, 0, 0);
                    x = __builtin_amdgcn_mfma_f32_16x16x32_bf16(pa[mt][1], vb[nt][1], x, 0, 0, 0);
                    o[mt][nt] = x;
                }
            }
        }
    }

    if (spart == 0) ls[srow] = l_run;
    __syncthreads();

    float* Ob = Out + bQoff;
    #pragma unroll
    for (int mt = 0; mt < 2; ++mt) {
        const float4 lv = *(const float4*)&ls[16 * mt + 4 * quad];
        const float inv[4] = {1.f / lv.x, 1.f / lv.y, 1.f / lv.z, 1.f / lv.w};
        #pragma unroll
        for (int nt = 0; nt < 2; ++nt)
            #pragma unroll
            for (int r = 0; r < 4; ++r)
                Ob[(size_t)(16 * mt + 4 * quad + r) * DH + 32 * wid + 16 * nt + l16] =
                    o[mt][nt][r] * inv[r];
    }
}

// ---- fallback (round-1 fp32 kernel) if ws is too small for bf16 staging ----
#define QSTRIDE (DH + 4)
#define PSTRIDE (BK + 4)
__global__ __launch_bounds__(NT, 2)
void attn_fwd(const float* __restrict__ Q, const float* __restrict__ K,
              const float* __restrict__ V, const int* __restrict__ vlens,
              float* __restrict__ Out) {
    __shared__ float Qs[BQ][QSTRIDE];
    __shared__ float KVs[BK][QSTRIDE];
    __shared__ float Ps[BQ][PSTRIDE];
    __shared__ float alpha_s[BQ];
    __shared__ float l_s[BQ];
    const int tid = threadIdx.x;
    const int b = blockIdx.y, q0 = blockIdx.x * BQ;
    const int vl = vlens[b];
    const float scale = 0.088388347648318441f;
    const float* Qb = Q + ((size_t)b * SEQ + q0) * DH;
    const float* Kb = K + (size_t)b * SEQ * DH;
    const float* Vb = V + (size_t)b * SEQ * DH;
    {
        const int r = tid >> 5, c4 = (tid & 31) * 4;
        #pragma unroll
        for (int i = 0; i < 4; ++i)
            *(float4*)&Qs[i * 8 + r][c4] = *(const float4*)(Qb + (size_t)(i * 8 + r) * DH + c4);
    }
    const int sty = tid >> 4, stx = tid & 15;
    const int brow = tid >> 3, bpart = tid & 7;
    const int prg = tid >> 5, pcg = tid & 31;
    float m_run = -1e30f, l_run = 0.0f;
    float O[4][4];
    #pragma unroll
    for (int i = 0; i < 4; ++i)
        #pragma unroll
        for (int j = 0; j < 4; ++j) O[i][j] = 0.0f;
    const int ntiles = (vl + BK - 1) / BK;
    for (int t = 0; t < ntiles; ++t) {
        const int k0 = t * BK;
        __syncthreads();
        {
            const int r = tid >> 5, c4 = (tid & 31) * 4;
            #pragma unroll
            for (int i = 0; i < 8; ++i)
                *(float4*)&KVs[i * 8 + r][c4] = *(const float4*)(Kb + (size_t)(k0 + i * 8 + r) * DH + c4);
        }
        __syncthreads();
        float s0[4] = {0.f, 0.f, 0.f, 0.f}, s1[4] = {0.f, 0.f, 0.f, 0.f};
        #pragma unroll 2
        for (int d = 0; d < DH; d += 4) {
            const float4 qa = *(const float4*)&Qs[2 * sty][d];
            const float4 qb = *(const float4*)&Qs[2 * sty + 1][d];
            #pragma unroll
            for (int j = 0; j < 4; ++j) {
                const float4 kk = *(const float4*)&KVs[4 * stx + j][d];
                s0[j] += qa.x * kk.x + qa.y * kk.y + qa.z * kk.z + qa.w * kk.w;
                s1[j] += qb.x * kk.x + qb.y * kk.y + qb.z * kk.z + qb.w * kk.w;
            }
        }
        #pragma unroll
        for (int j = 0; j < 4; ++j) {
            const int kk = k0 + 4 * stx + j;
            const bool valid = kk < vl;
            Ps[2 * sty][4 * stx + j] = valid ? s0[j] * scale : -1e30f;
            Ps[2 * sty + 1][4 * stx + j] = valid ? s1[j] * scale : -1e30f;
        }
        __syncthreads();
        float4 vreg[8];
        {
            const int r = tid >> 5, c4 = (tid & 31) * 4;
            #pragma unroll
            for (int i = 0; i < 8; ++i)
                vreg[i] = *(const float4*)(Vb + (size_t)(k0 + i * 8 + r) * DH + c4);
        }
        float vals[8], lm = -1e30f;
        #pragma unroll
        for (int i = 0; i < 8; ++i) { vals[i] = Ps[brow][bpart * 8 + i]; lm = fmaxf(lm, vals[i]); }
        #pragma unroll
        for (int off = 1; off < 8; off <<= 1) lm = fmaxf(lm, __shfl_xor(lm, off, 64));
        const float m_new = fmaxf(m_run, lm);
        const float alpha = __expf(m_run - m_new);
        float psum = 0.0f;
        #pragma unroll
        for (int i = 0; i < 8; ++i) {
            const float p = __expf(vals[i] - m_new);
            Ps[brow][bpart * 8 + i] = p;
            psum += p;
        }
        #pragma unroll
        for (int off = 1; off < 8; off <<= 1) psum += __shfl_xor(psum, off, 64);
        l_run = l_run * alpha + psum;
        m_run = m_new;
        if (bpart == 0) alpha_s[brow] = alpha;
        {
            const int r = tid >> 5, c4 = (tid & 31) * 4;
            #pragma unroll
            for (int i = 0; i < 8; ++i) *(float4*)&KVs[i * 8 + r][c4] = vreg[i];
        }
        __syncthreads();
        float al[4];
        #pragma unroll
        for (int i = 0; i < 4; ++i) al[i] = alpha_s[prg * 4 + i];
        #pragma unroll
        for (int i = 0; i < 4; ++i)
            #pragma unroll
            for (int j = 0; j < 4; ++j) O[i][j] *= al[i];
        for (int k = 0; k < BK; k += 4) {
            float4 pr[4];
            #pragma unroll
            for (int i = 0; i < 4; ++i) pr[i] = *(const float4*)&Ps[prg * 4 + i][k];
            #pragma unroll
            for (int k2 = 0; k2 < 4; ++k2) {
                const float4 vv = *(const float4*)&KVs[k + k2][pcg * 4];
                #pragma unroll
                for (int i = 0; i < 4; ++i) {
                    const float p = ((const float*)&pr[i])[k2];
                    O[i][0] += p * vv.x; O[i][1] += p * vv.y;
                    O[i][2] += p * vv.z; O[i][3] += p * vv.w;
                }
            }
        }
    }
    if (bpart == 0) l_s[brow] = l_run;
    __syncthreads();
    float* Ob = Out + ((size_t)b * SEQ + q0) * DH;
    #pragma unroll
    for (int i = 0; i < 4; ++i) {
        const int row = prg * 4 + i;
        const float inv = 1.0f / l_s[row];
        float4 o;
        o.x = O[i][0] * inv; o.y = O[i][1] * inv;
        o.z = O[i][2] * inv; o.w = O[i][3] * inv;
        *(float4*)(Ob + (size_t)row * DH + pcg * 4) = o;
    }
}

extern "C" void kernel_launch(void* const* d_in, const int* in_sizes, int n_in,
                              void* d_out, int out_size, void* d_ws, size_t ws_size,
                              hipStream_t stream) {
    const float* Q = (const float*)d_in[0];
    const float* K = (const float*)d_in[1];
    const float* V = (const float*)d_in[2];
    const int* vlens = (const int*)d_in[3];
    float* Out = (float*)d_out;

    const size_t n = (size_t)BS * SEQ * DH;   // 2,097,152 elements
    const size_t need = 5 * n * sizeof(unsigned short);   // 20 MiB

    if (ws_size >= need) {
        unsigned short* Qhi = (unsigned short*)d_ws;
        unsigned short* Qlo = Qhi + n;
        unsigned short* Khi = Qlo + n;
        unsigned short* Klo = Khi + n;
        unsigned short* Vt  = Klo + n;

        conv_hilo<<<dim3((2 * n / 4) / NT), dim3(NT), 0, stream>>>(Q, K, Qhi, Qlo, Khi, Klo);
        conv_vt<<<dim3(SEQ / 128, BS), dim3(NT), 0, stream>>>(V, Vt);
        attn_mfma<<<dim3(SEQ / BQ, BS), dim3(NT), 0, stream>>>(Qhi, Qlo, Khi, Klo, Vt, vlens, Out);
    } else {
        attn_fwd<<<dim3(SEQ / BQ, BS), dim3(NT), 0, stream>>>(Q, K, V, vlens, Out);
    }
}

// Round 3
// 137.324 us; speedup vs baseline: 2.8665x; 1.0818x over previous
//
#include <hip/hip_runtime.h>

typedef float f32x4 __attribute__((ext_vector_type(4)));
typedef short bf16x8 __attribute__((ext_vector_type(8)));

#define BS   8
#define SEQ  2048
#define DH   128
#define BQ   64
#define BK   64
#define NT   256
#define PST  72          // P bf16 per-wave row stride (ushort)

__device__ __forceinline__ unsigned short f2bf(float x) {
    unsigned u = __float_as_uint(x);
    u += 0x7FFFu + ((u >> 16) & 1u);   // RNE
    return (unsigned short)(u >> 16);
}

// async 16B global->LDS (lds dest = wave-uniform base + lane*16)
__device__ __forceinline__ void gl_lds16(const unsigned short* g, unsigned short* l) {
    __builtin_amdgcn_global_load_lds(
        (const __attribute__((address_space(1))) unsigned int*)g,
        (__attribute__((address_space(3))) unsigned int*)l, 16, 0, 0);
}

// ---- pre-pass 1: Q,K -> bf16 flat ----
__global__ __launch_bounds__(NT)
void conv_bf(const float* __restrict__ Q, const float* __restrict__ K,
             unsigned short* __restrict__ Qbf, unsigned short* __restrict__ Kbf) {
    const int gid = blockIdx.x * NT + threadIdx.x;
    const int half = (BS * SEQ * DH) / 4;
    const float* src;
    unsigned short* dst;
    int idx;
    if (gid < half) { src = Q; dst = Qbf; idx = gid; }
    else            { src = K; dst = Kbf; idx = gid - half; }
    float4 v = ((const float4*)src)[idx];
    ushort4 h;
    h.x = f2bf(v.x); h.y = f2bf(v.y); h.z = f2bf(v.z); h.w = f2bf(v.w);
    ((ushort4*)dst)[idx] = h;
}

// ---- pre-pass 2: V[b][s][d] -> Vt[b][d][s] bf16; 256 blocks of 64s x 128d ----
__global__ __launch_bounds__(NT)
void conv_vt(const float* __restrict__ V, unsigned short* __restrict__ Vt) {
    __shared__ unsigned short T[64][132];
    const int tid = threadIdx.x;
    const int b = blockIdx.y, s0 = blockIdx.x * 64;
    const float* Vb = V + ((size_t)b * SEQ + s0) * DH;
    #pragma unroll
    for (int i = 0; i < 8; ++i) {
        const int row = i * 8 + (tid >> 5);
        const int col = (tid & 31) * 4;
        float4 v = *(const float4*)(Vb + (size_t)row * DH + col);
        ushort4 h;
        h.x = f2bf(v.x); h.y = f2bf(v.y); h.z = f2bf(v.z); h.w = f2bf(v.w);
        *(ushort4*)&T[row][col] = h;
    }
    __syncthreads();
    const int d = tid >> 1, sh = (tid & 1) * 32;
    unsigned short tmp[32] __attribute__((aligned(16)));
    #pragma unroll
    for (int s = 0; s < 32; ++s) tmp[s] = T[sh + s][d];
    unsigned short* dst = Vt + ((size_t)b * DH + d) * SEQ + s0 + sh;
    #pragma unroll
    for (int g = 0; g < 4; ++g)
        *(uint4*)(dst + g * 8) = *(const uint4*)(tmp + g * 8);
}

// ---- main: flash attention, bf16 MFMA, wave-private softmax, dbuf async staging ----
__global__ __launch_bounds__(NT, 2)
void attn_mfma(const unsigned short* __restrict__ Qbf, const unsigned short* __restrict__ Kbf,
               const unsigned short* __restrict__ Vt, const int* __restrict__ vlens,
               float* __restrict__ Out) {
    // K tiles: 64 s-rows x 128 d (256 B rows, 16B chunks XOR-swizzled by row&15)
    // V tiles: 128 d-rows x 64 s (128 B rows, 16B chunks XOR-swizzled by row&7)
    __shared__ unsigned short Ks[2][BK * DH];
    __shared__ unsigned short Vs[2][DH * BK];
    __shared__ unsigned short Pb[4][16 * PST];

    const int tid  = threadIdx.x;
    const int wid  = tid >> 6, lane = tid & 63;
    const int quad = lane >> 4, l16 = lane & 15;
    const int b = blockIdx.y, q0 = blockIdx.x * BQ;
    const int vl = vlens[b];
    const float scale = 0.088388347648318441f;   // 1/sqrt(128)

    const unsigned short* Kb  = Kbf + (size_t)b * SEQ * DH;
    const unsigned short* Vtb = Vt  + (size_t)b * DH * SEQ;
    unsigned short* Pw = &Pb[wid][0];

    // Q A-fragments in registers for the whole K-loop:
    // lane m=l16 -> q-row (qw+l16); k = 8*quad + j (+32*ks)
    const int qw = q0 + 16 * wid;
    bf16x8 qf[4];
    #pragma unroll
    for (int ks = 0; ks < 4; ++ks)
        qf[ks] = *(const bf16x8*)(Qbf + ((size_t)(b * SEQ + qw + l16)) * DH + 32 * ks + 8 * quad);

    f32x4 o[8];
    #pragma unroll
    for (int n = 0; n < 8; ++n) o[n] = (f32x4){0.f, 0.f, 0.f, 0.f};
    float mrun[4] = {-1e30f, -1e30f, -1e30f, -1e30f};
    float lrun[4] = {0.f, 0.f, 0.f, 0.f};

    const int ntiles = (vl + BK - 1) / BK;

    // --- staging lambda: this wave stages K rows 16w..+15 and V d-rows 32w..+31 ---
    auto stage = [&](int buf, int k0) {
        unsigned short* KsB = &Ks[buf][0];
        unsigned short* VsB = &Vs[buf][0];
        #pragma unroll
        for (int ii = 0; ii < 4; ++ii) {
            const int rb = 16 * wid + 4 * ii;          // wave-uniform
            const int r  = rb + (lane >> 4);
            const int c  = lane & 15;
            gl_lds16(Kb + (size_t)(k0 + r) * DH + (((c ^ (r & 15))) << 3),
                     KsB + (size_t)rb * DH);
        }
        #pragma unroll
        for (int jj = 0; jj < 4; ++jj) {
            const int db = 32 * wid + 8 * jj;          // wave-uniform
            const int d  = db + (lane >> 3);
            const int c  = lane & 7;
            gl_lds16(Vtb + (size_t)d * SEQ + k0 + (((c ^ (d & 7))) << 3),
                     VsB + (size_t)db * BK);
        }
    };

    stage(0, 0);

    for (int t = 0; t < ntiles; ++t) {
        const int k0 = t * BK;
        __syncthreads();   // drains vmcnt(0): buf[t&1] staged; prev reads done
        if (t + 1 < ntiles) stage((t + 1) & 1, k0 + BK);

        const unsigned short* Kt = &Ks[t & 1][0];
        const unsigned short* Vtl = &Vs[t & 1][0];

        // ---- S = Q K^T : wave's 16 q-rows x 64 s-cols ----
        f32x4 s[4];
        #pragma unroll
        for (int nt = 0; nt < 4; ++nt) s[nt] = (f32x4){0.f, 0.f, 0.f, 0.f};
        #pragma unroll
        for (int ks = 0; ks < 4; ++ks) {
            bf16x8 bk[4];
            #pragma unroll
            for (int nt = 0; nt < 4; ++nt)
                bk[nt] = *(const bf16x8*)(Kt + (size_t)(16 * nt + l16) * DH +
                                          (((4 * ks + quad) ^ l16) << 3));
            #pragma unroll
            for (int nt = 0; nt < 4; ++nt)
                s[nt] = __builtin_amdgcn_mfma_f32_16x16x32_bf16(qf[ks], bk[nt], s[nt], 0, 0, 0);
        }

        // ---- wave-private online softmax (rows 4*quad+r, cols 16*nt+l16) ----
        float sv[4][4];
        #pragma unroll
        for (int nt = 0; nt < 4; ++nt) {
            const bool valid = (k0 + 16 * nt + l16) < vl;
            #pragma unroll
            for (int r = 0; r < 4; ++r)
                sv[nt][r] = valid ? s[nt][r] * scale : -1e30f;
        }
        float al[4];
        #pragma unroll
        for (int r = 0; r < 4; ++r) {
            float mx = fmaxf(fmaxf(sv[0][r], sv[1][r]), fmaxf(sv[2][r], sv[3][r]));
            mx = fmaxf(mx, __shfl_xor(mx, 1, 64));
            mx = fmaxf(mx, __shfl_xor(mx, 2, 64));
            mx = fmaxf(mx, __shfl_xor(mx, 4, 64));
            mx = fmaxf(mx, __shfl_xor(mx, 8, 64));
            const float mnew = fmaxf(mrun[r], mx);
            al[r] = __expf(mrun[r] - mnew);
            float rs = 0.f;
            #pragma unroll
            for (int nt = 0; nt < 4; ++nt) {
                const float p = __expf(sv[nt][r] - mnew);
                rs += p;
                Pw[(size_t)(4 * quad + r) * PST + 16 * nt + l16] = f2bf(p);
            }
            rs += __shfl_xor(rs, 1, 64);
            rs += __shfl_xor(rs, 2, 64);
            rs += __shfl_xor(rs, 4, 64);
            rs += __shfl_xor(rs, 8, 64);
            lrun[r] = lrun[r] * al[r] + rs;
            mrun[r] = mnew;
        }

        // ---- O = O*alpha + P V (wave-private P; lgkmcnt dependency only) ----
        #pragma unroll
        for (int n = 0; n < 8; ++n)
            #pragma unroll
            for (int r = 0; r < 4; ++r) o[n][r] *= al[r];
        #pragma unroll
        for (int kk = 0; kk < 2; ++kk) {
            const bf16x8 pa = *(const bf16x8*)(Pw + (size_t)l16 * PST + 32 * kk + 8 * quad);
            #pragma unroll
            for (int n = 0; n < 8; ++n) {
                const bf16x8 vb = *(const bf16x8*)(Vtl + (size_t)(16 * n + l16) * BK +
                                                   (((4 * kk + quad) ^ (l16 & 7)) << 3));
                o[n] = __builtin_amdgcn_mfma_f32_16x16x32_bf16(pa, vb, o[n], 0, 0, 0);
            }
        }
    }

    // ---- epilogue: normalize, store (rows 4*quad+r, cols 16*n+l16) ----
    float inv[4];
    #pragma unroll
    for (int r = 0; r < 4; ++r) inv[r] = 1.0f / lrun[r];
    #pragma unroll
    for (int r = 0; r < 4; ++r) {
        float* Ob = Out + ((size_t)b * SEQ + qw + 4 * quad + r) * DH;
        #pragma unroll
        for (int n = 0; n < 8; ++n)
            Ob[16 * n + l16] = o[n][r] * inv[r];
    }
}

extern "C" void kernel_launch(void* const* d_in, const int* in_sizes, int n_in,
                              void* d_out, int out_size, void* d_ws, size_t ws_size,
                              hipStream_t stream) {
    const float* Q = (const float*)d_in[0];
    const float* K = (const float*)d_in[1];
    const float* V = (const float*)d_in[2];
    const int* vlens = (const int*)d_in[3];
    float* Out = (float*)d_out;

    const size_t n = (size_t)BS * SEQ * DH;   // 2,097,152
    unsigned short* Qbf = (unsigned short*)d_ws;
    unsigned short* Kbf = Qbf + n;
    unsigned short* Vtw = Kbf + n;

    conv_bf<<<dim3((2 * (n / 4)) / NT), dim3(NT), 0, stream>>>(Q, K, Qbf, Kbf);
    conv_vt<<<dim3(SEQ / 64, BS), dim3(NT), 0, stream>>>(V, Vtw);
    attn_mfma<<<dim3(SEQ / BQ, BS), dim3(NT), 0, stream>>>(Qbf, Kbf, Vtw, vlens, Out);
}